// Round 13
// baseline (266.053 us; speedup 1.0000x reference)
//
#include <hip/hip_runtime.h>

#define N_NODES 50000
#define N_EDGES 800000
#define D 128
#define N_GRAPHS 256
#define N_CLASSES 16
#define BKT 64                            // CSR bucket slots per node
#define NGEMM ((N_NODES + 63) / 64)       // 782
#define NPRE ((N_EDGES + 255) / 256)      // 3125

typedef unsigned short ushort_t;
typedef unsigned int uint_t;
typedef __attribute__((ext_vector_type(8))) short bf16x8;
typedef __attribute__((ext_vector_type(4))) float f32x4;
typedef __attribute__((ext_vector_type(4))) int i32x4;

__device__ __forceinline__ float bf2f(uint_t u) {
  return __uint_as_float(u << 16);
}
__device__ __forceinline__ uint_t f2bf(float f) {
  uint_t x = __float_as_uint(f);
  return (x + 0x7fffu + ((x >> 16) & 1u)) >> 16;
}
__device__ __forceinline__ void fma8(float* acc, float w, uint4 v) {
  acc[0] = fmaf(w, bf2f(v.x & 0xffffu), acc[0]);
  acc[1] = fmaf(w, bf2f(v.x >> 16), acc[1]);
  acc[2] = fmaf(w, bf2f(v.y & 0xffffu), acc[2]);
  acc[3] = fmaf(w, bf2f(v.y >> 16), acc[3]);
  acc[4] = fmaf(w, bf2f(v.z & 0xffffu), acc[4]);
  acc[5] = fmaf(w, bf2f(v.z >> 16), acc[5]);
  acc[6] = fmaf(w, bf2f(v.w & 0xffffu), acc[6]);
  acc[7] = fmaf(w, bf2f(v.w >> 16), acc[7]);
}

// ---- K0: W-fragment packing + per-graph 1/cnt (tiny, runs first) ----
__global__ __launch_bounds__(256) void k_prep0(const float* __restrict__ W1,
                                               const float* __restrict__ W2,
                                               uint4* __restrict__ W1f,
                                               uint4* __restrict__ W2f,
                                               const int* __restrict__ batch,
                                               float* __restrict__ rcnts) {
  int t = threadIdx.x;
  int b = blockIdx.x;
  if (b < 16) {  // W-prep
    int slot = b * 256 + t;  // 0..4095
    const float* W = (slot < 2048) ? W1 : W2;
    uint4* Wf = (slot < 2048) ? W1f : W2f;
    int sl = slot & 2047;
    int lane = sl & 63;
    int s = (sl >> 6) & 3;
    int n = sl >> 8;
    int col = n * 16 + (lane & 15);
    int k0 = s * 32 + (lane >> 4) * 8;
    uint4 o;
    o.x = f2bf(W[(size_t)(k0 + 0) * D + col]) | (f2bf(W[(size_t)(k0 + 1) * D + col]) << 16);
    o.y = f2bf(W[(size_t)(k0 + 2) * D + col]) | (f2bf(W[(size_t)(k0 + 3) * D + col]) << 16);
    o.z = f2bf(W[(size_t)(k0 + 4) * D + col]) | (f2bf(W[(size_t)(k0 + 5) * D + col]) << 16);
    o.w = f2bf(W[(size_t)(k0 + 6) * D + col]) | (f2bf(W[(size_t)(k0 + 7) * D + col]) << 16);
    Wf[sl] = o;
    return;
  }
  // rcnts: batch sorted -> binary-search graph boundaries
  __shared__ int bound[257];
  {
    int g = t;
    int lo = 0, hi = N_NODES;
    while (lo < hi) {
      int m = (lo + hi) >> 1;
      if (batch[m] < g) lo = m + 1; else hi = m;
    }
    bound[g] = lo;
    if (t == 255) bound[256] = N_NODES;
  }
  __syncthreads();
  int cnt = bound[t + 1] - bound[t];
  rcnts[t] = 1.0f / (float)max(cnt, 1);
}

// GEMM core: 64-row tile @ Wf -> bf16 out (NO dinv scaling). LDS-staged A.
template <typename TIN>
__device__ __forceinline__ void gemm_body(const TIN* __restrict__ A,
                                          const uint4* __restrict__ Wf,
                                          ushort_t* __restrict__ Out,
                                          uint4* As, int bid, int t) {
  int row0 = bid * 64;
  if constexpr (sizeof(TIN) == 4) {  // fp32 input: coalesced float4 loads
    uint2* As2 = (uint2*)As;
#pragma unroll
    for (int i = 0; i < 8; ++i) {
      int F = t + 256 * i;      // float4 id
      int r = F >> 5, f = F & 31;
      int grow = row0 + r;
      uint2 u = make_uint2(0, 0);
      if (grow < N_NODES) {
        float4 v = *(const float4*)(A + (size_t)grow * D + f * 4);
        u.x = f2bf(v.x) | (f2bf(v.y) << 16);
        u.y = f2bf(v.z) | (f2bf(v.w) << 16);
      }
      int g = f >> 1;
      As2[(r * 16 + (g ^ (r & 7))) * 2 + (f & 1)] = u;
    }
  } else {  // bf16 input: coalesced 16B loads
#pragma unroll
    for (int i = 0; i < 4; ++i) {
      int G = t + 256 * i;      // granule id
      int r = G >> 4, g = G & 15;
      int grow = row0 + r;
      uint4 u = make_uint4(0, 0, 0, 0);
      if (grow < N_NODES) u = *(const uint4*)(A + (size_t)grow * D + g * 8);
      As[r * 16 + (g ^ (r & 7))] = u;
    }
  }
  __syncthreads();
  int wv = t >> 6, lane = t & 63;
  int row16 = lane & 15, chunk = lane >> 4;
  int rl = wv * 16 + row16;
  bf16x8 afrag[4];
#pragma unroll
  for (int s = 0; s < 4; ++s) {
    int g = s * 4 + chunk;
    afrag[s] = *(const bf16x8*)&As[rl * 16 + (g ^ (rl & 7))];
  }
  f32x4 acc[8];
#pragma unroll
  for (int n = 0; n < 8; ++n) acc[n] = (f32x4){0.f, 0.f, 0.f, 0.f};
  const bf16x8* Wb = (const bf16x8*)Wf;
#pragma unroll
  for (int n = 0; n < 8; ++n) {
#pragma unroll
    for (int s = 0; s < 4; ++s) {
      bf16x8 b = Wb[(n * 4 + s) * 64 + lane];
      acc[n] = __builtin_amdgcn_mfma_f32_16x16x32_bf16(afrag[s], b, acc[n], 0, 0, 0);
    }
  }
  int crow0 = row0 + wv * 16 + chunk * 4;  // C/D: col=lane&15, row=(lane>>4)*4+reg
#pragma unroll
  for (int n = 0; n < 8; ++n) {
#pragma unroll
    for (int j = 0; j < 4; ++j) {
      int r = crow0 + j;
      if (r < N_NODES)
        Out[(size_t)r * D + n * 16 + row16] = (ushort_t)f2bf(acc[n][j]);
    }
  }
}

// ---- K1 mega: [pre(hist+bucket-CSR) | gemm1] — mutually independent ----
// pre blocks first (long pole); gemm1 reads W1f written by k_prep0 (prior kernel).
__global__ __launch_bounds__(256) void k_mega(const float* __restrict__ x,
                                              const int* __restrict__ ei,
                                              const uint4* __restrict__ W1f,
                                              int* __restrict__ deg,
                                              int* __restrict__ csr,
                                              ushort_t* __restrict__ hbuf) {
  __shared__ uint4 As[1024];  // gemm path only (16 KB)
  int t = threadIdx.x;
  int b = blockIdx.x;
  if (b < NPRE) {  // pre: histogram + direct-bucket CSR
    int e = b * 256 + t;
    if (e < N_EDGES) {
      int s = ei[e];
      int d = ei[N_EDGES + e];
      int r = atomicAdd(&deg[d], 1);
      if (r < BKT) __builtin_nontemporal_store(s, csr + d * BKT + r);
    }
    return;
  }
  gemm_body<float>(x, W1f, hbuf, As, b - NPRE, t);
}

// ---- bf16-input GEMM (layer 2), unscaled ----
__global__ __launch_bounds__(256) void k_gemm2(const ushort_t* __restrict__ A,
                                               const uint4* __restrict__ Wf,
                                               ushort_t* __restrict__ Out) {
  __shared__ uint4 As[1024];
  gemm_body<ushort_t>(A, Wf, Out, As, blockIdx.x, threadIdx.x);
}

// ---- edge loop: wave per node, 16 edges/iter; weight = rsqrt(deg[s]+1) ----
__device__ __forceinline__ void agg_core(const ushort_t* __restrict__ h,
                                         const int* __restrict__ csr,
                                         const int* __restrict__ deg,
                                         int beg, int end, int grp, int d0,
                                         float* acc) {
  for (int wb = beg; wb < end; wb += 16) {
    int i0 = wb + grp * 4;
    i32x4 s4 = __builtin_nontemporal_load((const i32x4*)(csr + i0));
    bool b0 = i0 < end, b1 = i0 + 1 < end, b2 = i0 + 2 < end, b3 = i0 + 3 < end;
    uint4 v0, v1, v2, v3;
    float w0 = 0.f, w1 = 0.f, w2 = 0.f, w3 = 0.f;
    if (b0) { v0 = *(const uint4*)(h + (size_t)s4.x * D + d0); w0 = rsqrtf((float)(deg[s4.x] + 1)); }
    if (b1) { v1 = *(const uint4*)(h + (size_t)s4.y * D + d0); w1 = rsqrtf((float)(deg[s4.y] + 1)); }
    if (b2) { v2 = *(const uint4*)(h + (size_t)s4.z * D + d0); w2 = rsqrtf((float)(deg[s4.z] + 1)); }
    if (b3) { v3 = *(const uint4*)(h + (size_t)s4.w * D + d0); w3 = rsqrtf((float)(deg[s4.w] + 1)); }
    if (b0) fma8(acc, w0, v0);
    if (b1) fma8(acc, w1, v1);
    if (b2) fma8(acc, w2, v2);
    if (b3) fma8(acc, w3, v3);
  }
}

// ---- agg layer1: wave per node; out = relu(dinv_n*(sum + dinv_n*h_n) + b1) ----
__global__ __launch_bounds__(256) void k_agg_relu(const ushort_t* __restrict__ h,
                                                  const int* __restrict__ csr,
                                                  const int* __restrict__ deg,
                                                  const float* __restrict__ bias,
                                                  ushort_t* __restrict__ obf) {
  int t = threadIdx.x;
  int wv = t >> 6, lane = t & 63;
  int grp = lane >> 4, gl = lane & 15;
  int d0 = gl * 8;
  int node = blockIdx.x * 4 + wv;  // N_NODES % 4 == 0
  int dn_i = deg[node];
  int beg = node * BKT, end = beg + min(dn_i, BKT);
  float acc[8] = {0.f, 0.f, 0.f, 0.f, 0.f, 0.f, 0.f, 0.f};
  agg_core(h, csr, deg, beg, end, grp, d0, acc);
#pragma unroll
  for (int m = 16; m <= 32; m <<= 1) {
#pragma unroll
    for (int i = 0; i < 8; ++i) acc[i] += __shfl_xor(acc[i], m);
  }
  if (grp == 0) {
    float dn = rsqrtf((float)(dn_i + 1));
    uint4 v = *(const uint4*)(h + (size_t)node * D + d0);  // self h
    fma8(acc, dn, v);
    float4 blo = *(const float4*)(bias + d0);
    float4 bhi = *(const float4*)(bias + d0 + 4);
    acc[0] = fmaf(acc[0], dn, blo.x);
    acc[1] = fmaf(acc[1], dn, blo.y);
    acc[2] = fmaf(acc[2], dn, blo.z);
    acc[3] = fmaf(acc[3], dn, blo.w);
    acc[4] = fmaf(acc[4], dn, bhi.x);
    acc[5] = fmaf(acc[5], dn, bhi.y);
    acc[6] = fmaf(acc[6], dn, bhi.z);
    acc[7] = fmaf(acc[7], dn, bhi.w);
#pragma unroll
    for (int i = 0; i < 8; ++i) acc[i] = fmaxf(acc[i], 0.f);
    uint4 o;
    o.x = f2bf(acc[0]) | (f2bf(acc[1]) << 16);
    o.y = f2bf(acc[2]) | (f2bf(acc[3]) << 16);
    o.z = f2bf(acc[4]) | (f2bf(acc[5]) << 16);
    o.w = f2bf(acc[6]) | (f2bf(acc[7]) << 16);
    *(uint4*)(obf + (size_t)node * D + d0) = o;
  }
}

// ---- agg layer2 + mean-pool: 16 waves/block, wave per node ----
__global__ __launch_bounds__(1024) void k_agg_pool(const ushort_t* __restrict__ h,
                                                   const int* __restrict__ csr,
                                                   const int* __restrict__ deg,
                                                   const int* __restrict__ batch,
                                                   const float* __restrict__ rcnts,
                                                   float* __restrict__ sums) {
  __shared__ float pool2[16][128];  // 8 KB
  int t = threadIdx.x;
  int wv = t >> 6, lane = t & 63;
  int grp = lane >> 4, gl = lane & 15;
  int d0 = gl * 8;
  int node0 = blockIdx.x * 16;  // N_NODES % 16 == 0
  int node = node0 + wv;
  int g0 = batch[node0];
  int dn_i = deg[node];
  int beg = node * BKT, end = beg + min(dn_i, BKT);
  float acc[8] = {0.f, 0.f, 0.f, 0.f, 0.f, 0.f, 0.f, 0.f};
  agg_core(h, csr, deg, beg, end, grp, d0, acc);
#pragma unroll
  for (int m = 16; m <= 32; m <<= 1) {
#pragma unroll
    for (int k = 0; k < 8; ++k) acc[k] += __shfl_xor(acc[k], m);
  }
  if (grp == 0) {
    float dn = rsqrtf((float)(dn_i + 1));
    uint4 v = *(const uint4*)(h + (size_t)node * D + d0);  // self h
    fma8(acc, dn, v);
    int g = batch[node];
    float sc = dn * rcnts[g];
    if (g == g0) {
#pragma unroll
      for (int k = 0; k < 8; ++k) pool2[wv][d0 + k] = acc[k] * sc;
    } else {
#pragma unroll
      for (int k = 0; k < 8; ++k) {
        pool2[wv][d0 + k] = 0.f;
        atomicAdd(&sums[(size_t)g * D + d0 + k], acc[k] * sc);
      }
    }
  }
  __syncthreads();
  if (t < 128) {
    float s = 0.f;
#pragma unroll
    for (int w = 0; w < 16; ++w) s += pool2[w][t];
    atomicAdd(&sums[(size_t)g0 * D + t], s);
  }
}

// ---- mean(+b2) + final linear head ----
__global__ __launch_bounds__(128) void k_final(const float* __restrict__ sums,
                                               const float* __restrict__ b2,
                                               const float* __restrict__ Wc,
                                               const float* __restrict__ bc,
                                               float* __restrict__ out) {
  __shared__ float p[128];
  int g = blockIdx.x;
  int t = threadIdx.x;
  p[t] = sums[g * D + t] + b2[t];
  __syncthreads();
  if (t < N_CLASSES) {
    float acc = bc[t];
    for (int k = 0; k < D; ++k) acc = fmaf(p[k], Wc[k * N_CLASSES + t], acc);
    out[g * N_CLASSES + t] = acc;
  }
}

extern "C" void kernel_launch(void* const* d_in, const int* in_sizes, int n_in,
                              void* d_out, int out_size, void* d_ws, size_t ws_size,
                              hipStream_t stream) {
  const float* x = (const float*)d_in[0];
  const int* ei = (const int*)d_in[1];
  const int* batch = (const int*)d_in[2];
  const float* W1 = (const float*)d_in[3];
  const float* b1 = (const float*)d_in[4];
  const float* W2 = (const float*)d_in[5];
  const float* b2 = (const float*)d_in[6];
  const float* Wc = (const float*)d_in[7];
  const float* bc = (const float*)d_in[8];
  float* out = (float*)d_out;

  char* ws = (char*)d_ws;
  size_t off = 0;
  auto alloc = [&](size_t bytes) -> void* {
    void* p = (void*)(ws + off);
    off += (bytes + 255) & ~(size_t)255;
    return p;
  };
  // zero-init region: deg, sums contiguous at the front
  int* deg = (int*)alloc((size_t)N_NODES * 4);
  float* sums = (float*)alloc((size_t)N_GRAPHS * D * 4);
  size_t zero_bytes = off;
  float* rcnts = (float*)alloc((size_t)N_GRAPHS * 4);
  uint4* W1f = (uint4*)alloc((size_t)2048 * 16);
  uint4* W2f = (uint4*)alloc((size_t)2048 * 16);
  int* csr = (int*)alloc((size_t)N_NODES * BKT * 4);           // 12.8 MB buckets
  ushort_t* hbuf = (ushort_t*)alloc((size_t)N_NODES * D * 2);  // h (bf16, unscaled)
  ushort_t* x2 = (ushort_t*)alloc((size_t)N_NODES * D * 2);    // relu out bf16

  hipMemsetAsync(ws, 0, zero_bytes, stream);

  k_prep0<<<17, 256, 0, stream>>>(W1, W2, W1f, W2f, batch, rcnts);
  k_mega<<<NPRE + NGEMM, 256, 0, stream>>>(x, ei, (const uint4*)W1f, deg, csr, hbuf);
  k_agg_relu<<<N_NODES / 4, 256, 0, stream>>>(hbuf, csr, deg, b1, x2);
  k_gemm2<<<NGEMM, 256, 0, stream>>>(x2, (const uint4*)W2f, hbuf);
  k_agg_pool<<<N_NODES / 16, 1024, 0, stream>>>(hbuf, csr, deg, batch, rcnts, sums);
  k_final<<<N_GRAPHS, 128, 0, stream>>>(sums, b2, Wc, bc, out);
}

// Round 14
// 224.120 us; speedup vs baseline: 1.1871x; 1.1871x over previous
//
#include <hip/hip_runtime.h>

#define N_NODES 50000
#define N_EDGES 800000
#define D 128
#define N_GRAPHS 256
#define N_CLASSES 16
#define BKT 64                            // CSR bucket slots per node
#define NBKT 196                          // coarse buckets (dst>>8), 50000/256
#define CAP 4608                          // coarse bucket capacity (mean 4096, +8 sigma)
#define NB_A ((N_EDGES + 1023) / 1024)    // 782 pass-A blocks
#define NGEMM ((N_NODES + 255) / 256)     // 196 gemm blocks (256 rows each)

typedef unsigned short ushort_t;
typedef unsigned int uint_t;
typedef unsigned char uchar_t;
typedef __attribute__((ext_vector_type(8))) short bf16x8;
typedef __attribute__((ext_vector_type(4))) float f32x4;
typedef __attribute__((ext_vector_type(4))) int i32x4;

__device__ __forceinline__ float bf2f(uint_t u) {
  return __uint_as_float(u << 16);
}
__device__ __forceinline__ uint_t f2bf(float f) {
  uint_t x = __float_as_uint(f);
  return (x + 0x7fffu + ((x >> 16) & 1u)) >> 16;
}
__device__ __forceinline__ void fma8(float* acc, float w, uint4 v) {
  acc[0] = fmaf(w, bf2f(v.x & 0xffffu), acc[0]);
  acc[1] = fmaf(w, bf2f(v.x >> 16), acc[1]);
  acc[2] = fmaf(w, bf2f(v.y & 0xffffu), acc[2]);
  acc[3] = fmaf(w, bf2f(v.y >> 16), acc[3]);
  acc[4] = fmaf(w, bf2f(v.z & 0xffffu), acc[4]);
  acc[5] = fmaf(w, bf2f(v.z >> 16), acc[5]);
  acc[6] = fmaf(w, bf2f(v.w & 0xffffu), acc[6]);
  acc[7] = fmaf(w, bf2f(v.w >> 16), acc[7]);
}

// ---- K1: [passA: coarse-bin edges | W-prep | rcnts] (1024 threads) ----
__global__ __launch_bounds__(1024) void k_bin(const int* __restrict__ ei,
                                              const int* __restrict__ batch,
                                              const float* __restrict__ W1,
                                              const float* __restrict__ W2,
                                              int* __restrict__ gcur,
                                              uint_t* __restrict__ gbuf,
                                              uint4* __restrict__ W1f,
                                              uint4* __restrict__ W2f,
                                              float* __restrict__ rcnts) {
  int t = threadIdx.x;
  int b = blockIdx.x;
  if (b < NB_A) {  // pass A: bin by dst>>8, pack src|(dst&255)<<17
    __shared__ int lhist[NBKT];
    __shared__ int lbase[NBKT];
    for (int i = t; i < NBKT; i += 1024) lhist[i] = 0;
    __syncthreads();
    int e = b * 1024 + t;
    bool ok = e < N_EDGES;
    int s = 0, d = 0, bk = 0, lr = 0;
    if (ok) {
      s = ei[e];
      d = ei[N_EDGES + e];
      bk = d >> 8;
      lr = atomicAdd(&lhist[bk], 1);
    }
    __syncthreads();
    for (int i = t; i < NBKT; i += 1024)
      lbase[i] = lhist[i] ? atomicAdd(&gcur[i], lhist[i]) : 0;
    __syncthreads();
    if (ok) {
      int pos = lbase[bk] + lr;
      if (pos < CAP) gbuf[bk * CAP + pos] = (uint_t)s | ((uint_t)(d & 255) << 17);
    }
    return;
  }
  b -= NB_A;
  if (b < 4) {  // W-prep: 4096 slots
    int slot = b * 1024 + t;
    const float* W = (slot < 2048) ? W1 : W2;
    uint4* Wf = (slot < 2048) ? W1f : W2f;
    int sl = slot & 2047;
    int lane = sl & 63;
    int s = (sl >> 6) & 3;
    int n = sl >> 8;
    int col = n * 16 + (lane & 15);
    int k0 = s * 32 + (lane >> 4) * 8;
    uint4 o;
    o.x = f2bf(W[(size_t)(k0 + 0) * D + col]) | (f2bf(W[(size_t)(k0 + 1) * D + col]) << 16);
    o.y = f2bf(W[(size_t)(k0 + 2) * D + col]) | (f2bf(W[(size_t)(k0 + 3) * D + col]) << 16);
    o.z = f2bf(W[(size_t)(k0 + 4) * D + col]) | (f2bf(W[(size_t)(k0 + 5) * D + col]) << 16);
    o.w = f2bf(W[(size_t)(k0 + 6) * D + col]) | (f2bf(W[(size_t)(k0 + 7) * D + col]) << 16);
    Wf[sl] = o;
    return;
  }
  // rcnts: batch sorted -> binary-search graph boundaries
  __shared__ int bound[257];
  if (t <= 256) {
    int g = t;
    int lo = 0, hi = N_NODES;
    while (lo < hi) {
      int m = (lo + hi) >> 1;
      if (batch[m] < g) lo = m + 1; else hi = m;
    }
    bound[g] = lo;
  }
  __syncthreads();
  if (t < 256) rcnts[t] = 1.0f / (float)max(bound[t + 1] - bound[t], 1);
}

// GEMM core: 256-row tile @ Wf -> bf16 out. 1024 threads, LDS-staged A.
template <typename TIN>
__device__ __forceinline__ void gemm_body(const TIN* __restrict__ A,
                                          const uint4* __restrict__ Wf,
                                          ushort_t* __restrict__ Out,
                                          uint4* As /*4096*/, int bid, int t) {
  int row0 = bid * 256;
  if constexpr (sizeof(TIN) == 4) {  // fp32: 8192 float4s, coalesced
    uint2* As2 = (uint2*)As;
#pragma unroll
    for (int i = 0; i < 8; ++i) {
      int F = t + 1024 * i;     // float4 id
      int r = F >> 5, f = F & 31;
      int grow = row0 + r;
      uint2 u = make_uint2(0, 0);
      if (grow < N_NODES) {
        float4 v = *(const float4*)(A + (size_t)grow * D + f * 4);
        u.x = f2bf(v.x) | (f2bf(v.y) << 16);
        u.y = f2bf(v.z) | (f2bf(v.w) << 16);
      }
      int g = f >> 1;
      As2[(r * 16 + (g ^ (r & 7))) * 2 + (f & 1)] = u;
    }
  } else {  // bf16: 4096 granules, coalesced 16B loads
#pragma unroll
    for (int i = 0; i < 4; ++i) {
      int G = t + 1024 * i;     // granule id
      int r = G >> 4, g = G & 15;
      int grow = row0 + r;
      uint4 u = make_uint4(0, 0, 0, 0);
      if (grow < N_NODES) u = *(const uint4*)(A + (size_t)grow * D + g * 8);
      As[r * 16 + (g ^ (r & 7))] = u;
    }
  }
  __syncthreads();
  int wv = t >> 6, lane = t & 63;   // wv 0..15
  int row16 = lane & 15, chunk = lane >> 4;
  int rl = wv * 16 + row16;         // 0..255
  bf16x8 afrag[4];
#pragma unroll
  for (int s = 0; s < 4; ++s) {
    int g = s * 4 + chunk;
    afrag[s] = *(const bf16x8*)&As[rl * 16 + (g ^ (rl & 7))];
  }
  f32x4 acc[8];
#pragma unroll
  for (int n = 0; n < 8; ++n) acc[n] = (f32x4){0.f, 0.f, 0.f, 0.f};
  const bf16x8* Wb = (const bf16x8*)Wf;
#pragma unroll
  for (int n = 0; n < 8; ++n) {
#pragma unroll
    for (int s = 0; s < 4; ++s) {
      bf16x8 b = Wb[(n * 4 + s) * 64 + lane];
      acc[n] = __builtin_amdgcn_mfma_f32_16x16x32_bf16(afrag[s], b, acc[n], 0, 0, 0);
    }
  }
  int crow0 = row0 + wv * 16 + chunk * 4;  // C/D: col=lane&15, row=(lane>>4)*4+reg
#pragma unroll
  for (int n = 0; n < 8; ++n) {
#pragma unroll
    for (int j = 0; j < 4; ++j) {
      int r = crow0 + j;
      if (r < N_NODES)
        Out[(size_t)r * D + n * 16 + row16] = (ushort_t)f2bf(acc[n][j]);
    }
  }
}

// ---- K2: [passB: per-bucket counting sort -> csr+deg | gemm1] ----
__global__ __launch_bounds__(1024) void k_sortgemm(const uint_t* __restrict__ gbuf,
                                                   const int* __restrict__ gcur,
                                                   const float* __restrict__ x,
                                                   const uint4* __restrict__ W1f,
                                                   int* __restrict__ deg,
                                                   int* __restrict__ csr,
                                                   ushort_t* __restrict__ hbuf) {
  __shared__ uint4 As[4096];  // 64 KB: gemm staging / reused as nothing in sort path
  int t = threadIdx.x;
  int b = blockIdx.x;
  if (b < NBKT) {  // pass B: counting-sort bucket b into node-slot CSR
    __shared__ int h2[256];
    __shared__ uchar_t rk[CAP];
    if (t < 256) h2[t] = 0;
    __syncthreads();
    int cnt = min(gcur[b], CAP);
    const uint_t* gb = gbuf + (size_t)b * CAP;
    for (int i = t; i < cnt; i += 1024)
      rk[i] = (uchar_t)atomicAdd(&h2[gb[i] >> 17], 1);
    __syncthreads();
    if (t < 256) {
      int node = b * 256 + t;
      if (node < N_NODES) deg[node] = min(h2[t], BKT);
    }
    for (int i = t; i < cnt; i += 1024) {
      uint_t p = gb[i];
      int node = b * 256 + (int)(p >> 17);
      int r = rk[i];
      if (r < BKT) csr[node * BKT + r] = (int)(p & 0x1FFFFu);
    }
    return;
  }
  gemm_body<float>(x, W1f, hbuf, As, b - NBKT, t);
}

// ---- bf16-input GEMM (layer 2) ----
__global__ __launch_bounds__(1024) void k_gemm2(const ushort_t* __restrict__ A,
                                                const uint4* __restrict__ Wf,
                                                ushort_t* __restrict__ Out) {
  __shared__ uint4 As[4096];
  gemm_body<ushort_t>(A, Wf, Out, As, blockIdx.x, threadIdx.x);
}

// ---- edge loop: wave per node, 16 edges/iter; weight = rsqrt(deg[s]+1) ----
__device__ __forceinline__ void agg_core(const ushort_t* __restrict__ h,
                                         const int* __restrict__ csr,
                                         const int* __restrict__ deg,
                                         int beg, int end, int grp, int d0,
                                         float* acc) {
  for (int wb = beg; wb < end; wb += 16) {
    int i0 = wb + grp * 4;
    i32x4 s4 = __builtin_nontemporal_load((const i32x4*)(csr + i0));
    bool b0 = i0 < end, b1 = i0 + 1 < end, b2 = i0 + 2 < end, b3 = i0 + 3 < end;
    uint4 v0, v1, v2, v3;
    float w0 = 0.f, w1 = 0.f, w2 = 0.f, w3 = 0.f;
    if (b0) { v0 = *(const uint4*)(h + (size_t)s4.x * D + d0); w0 = rsqrtf((float)(deg[s4.x] + 1)); }
    if (b1) { v1 = *(const uint4*)(h + (size_t)s4.y * D + d0); w1 = rsqrtf((float)(deg[s4.y] + 1)); }
    if (b2) { v2 = *(const uint4*)(h + (size_t)s4.z * D + d0); w2 = rsqrtf((float)(deg[s4.z] + 1)); }
    if (b3) { v3 = *(const uint4*)(h + (size_t)s4.w * D + d0); w3 = rsqrtf((float)(deg[s4.w] + 1)); }
    if (b0) fma8(acc, w0, v0);
    if (b1) fma8(acc, w1, v1);
    if (b2) fma8(acc, w2, v2);
    if (b3) fma8(acc, w3, v3);
  }
}

// ---- agg layer1: wave per node; out = relu(dinv_n*(sum + dinv_n*h_n) + b1) ----
__global__ __launch_bounds__(256) void k_agg_relu(const ushort_t* __restrict__ h,
                                                  const int* __restrict__ csr,
                                                  const int* __restrict__ deg,
                                                  const float* __restrict__ bias,
                                                  ushort_t* __restrict__ obf) {
  int t = threadIdx.x;
  int wv = t >> 6, lane = t & 63;
  int grp = lane >> 4, gl = lane & 15;
  int d0 = gl * 8;
  int node = blockIdx.x * 4 + wv;  // N_NODES % 4 == 0
  int dn_i = deg[node];
  int beg = node * BKT, end = beg + min(dn_i, BKT);
  float acc[8] = {0.f, 0.f, 0.f, 0.f, 0.f, 0.f, 0.f, 0.f};
  agg_core(h, csr, deg, beg, end, grp, d0, acc);
#pragma unroll
  for (int m = 16; m <= 32; m <<= 1) {
#pragma unroll
    for (int i = 0; i < 8; ++i) acc[i] += __shfl_xor(acc[i], m);
  }
  if (grp == 0) {
    float dn = rsqrtf((float)(dn_i + 1));
    uint4 v = *(const uint4*)(h + (size_t)node * D + d0);  // self h
    fma8(acc, dn, v);
    float4 blo = *(const float4*)(bias + d0);
    float4 bhi = *(const float4*)(bias + d0 + 4);
    acc[0] = fmaf(acc[0], dn, blo.x);
    acc[1] = fmaf(acc[1], dn, blo.y);
    acc[2] = fmaf(acc[2], dn, blo.z);
    acc[3] = fmaf(acc[3], dn, blo.w);
    acc[4] = fmaf(acc[4], dn, bhi.x);
    acc[5] = fmaf(acc[5], dn, bhi.y);
    acc[6] = fmaf(acc[6], dn, bhi.z);
    acc[7] = fmaf(acc[7], dn, bhi.w);
#pragma unroll
    for (int i = 0; i < 8; ++i) acc[i] = fmaxf(acc[i], 0.f);
    uint4 o;
    o.x = f2bf(acc[0]) | (f2bf(acc[1]) << 16);
    o.y = f2bf(acc[2]) | (f2bf(acc[3]) << 16);
    o.z = f2bf(acc[4]) | (f2bf(acc[5]) << 16);
    o.w = f2bf(acc[6]) | (f2bf(acc[7]) << 16);
    *(uint4*)(obf + (size_t)node * D + d0) = o;
  }
}

// ---- agg layer2 + mean-pool: 16 waves/block, wave per node ----
__global__ __launch_bounds__(1024) void k_agg_pool(const ushort_t* __restrict__ h,
                                                   const int* __restrict__ csr,
                                                   const int* __restrict__ deg,
                                                   const int* __restrict__ batch,
                                                   const float* __restrict__ rcnts,
                                                   float* __restrict__ sums) {
  __shared__ float pool2[16][128];  // 8 KB
  int t = threadIdx.x;
  int wv = t >> 6, lane = t & 63;
  int grp = lane >> 4, gl = lane & 15;
  int d0 = gl * 8;
  int node0 = blockIdx.x * 16;  // N_NODES % 16 == 0
  int node = node0 + wv;
  int g0 = batch[node0];
  int dn_i = deg[node];
  int beg = node * BKT, end = beg + min(dn_i, BKT);
  float acc[8] = {0.f, 0.f, 0.f, 0.f, 0.f, 0.f, 0.f, 0.f};
  agg_core(h, csr, deg, beg, end, grp, d0, acc);
#pragma unroll
  for (int m = 16; m <= 32; m <<= 1) {
#pragma unroll
    for (int k = 0; k < 8; ++k) acc[k] += __shfl_xor(acc[k], m);
  }
  if (grp == 0) {
    float dn = rsqrtf((float)(dn_i + 1));
    uint4 v = *(const uint4*)(h + (size_t)node * D + d0);  // self h
    fma8(acc, dn, v);
    int g = batch[node];
    float sc = dn * rcnts[g];
    if (g == g0) {
#pragma unroll
      for (int k = 0; k < 8; ++k) pool2[wv][d0 + k] = acc[k] * sc;
    } else {
#pragma unroll
      for (int k = 0; k < 8; ++k) {
        pool2[wv][d0 + k] = 0.f;
        atomicAdd(&sums[(size_t)g * D + d0 + k], acc[k] * sc);
      }
    }
  }
  __syncthreads();
  if (t < 128) {
    float s = 0.f;
#pragma unroll
    for (int w = 0; w < 16; ++w) s += pool2[w][t];
    atomicAdd(&sums[(size_t)g0 * D + t], s);
  }
}

// ---- mean(+b2) + final linear head ----
__global__ __launch_bounds__(128) void k_final(const float* __restrict__ sums,
                                               const float* __restrict__ b2,
                                               const float* __restrict__ Wc,
                                               const float* __restrict__ bc,
                                               float* __restrict__ out) {
  __shared__ float p[128];
  int g = blockIdx.x;
  int t = threadIdx.x;
  p[t] = sums[g * D + t] + b2[t];
  __syncthreads();
  if (t < N_CLASSES) {
    float acc = bc[t];
    for (int k = 0; k < D; ++k) acc = fmaf(p[k], Wc[k * N_CLASSES + t], acc);
    out[g * N_CLASSES + t] = acc;
  }
}

extern "C" void kernel_launch(void* const* d_in, const int* in_sizes, int n_in,
                              void* d_out, int out_size, void* d_ws, size_t ws_size,
                              hipStream_t stream) {
  const float* x = (const float*)d_in[0];
  const int* ei = (const int*)d_in[1];
  const int* batch = (const int*)d_in[2];
  const float* W1 = (const float*)d_in[3];
  const float* b1 = (const float*)d_in[4];
  const float* W2 = (const float*)d_in[5];
  const float* b2 = (const float*)d_in[6];
  const float* Wc = (const float*)d_in[7];
  const float* bc = (const float*)d_in[8];
  float* out = (float*)d_out;

  char* ws = (char*)d_ws;
  size_t off = 0;
  auto alloc = [&](size_t bytes) -> void* {
    void* p = (void*)(ws + off);
    off += (bytes + 255) & ~(size_t)255;
    return p;
  };
  // zero-init region: gcur + sums contiguous at the front
  int* gcur = (int*)alloc((size_t)NBKT * 4);
  float* sums = (float*)alloc((size_t)N_GRAPHS * D * 4);
  size_t zero_bytes = off;
  int* deg = (int*)alloc((size_t)N_NODES * 4);                 // written by passB
  float* rcnts = (float*)alloc((size_t)N_GRAPHS * 4);
  uint4* W1f = (uint4*)alloc((size_t)2048 * 16);
  uint4* W2f = (uint4*)alloc((size_t)2048 * 16);
  uint_t* gbuf = (uint_t*)alloc((size_t)NBKT * CAP * 4);       // 3.6 MB coarse bins
  int* csr = (int*)alloc((size_t)N_NODES * BKT * 4);           // 12.8 MB buckets
  ushort_t* hbuf = (ushort_t*)alloc((size_t)N_NODES * D * 2);  // h (bf16, unscaled)
  ushort_t* x2 = (ushort_t*)alloc((size_t)N_NODES * D * 2);    // relu out bf16

  hipMemsetAsync(ws, 0, zero_bytes, stream);

  k_bin<<<NB_A + 5, 1024, 0, stream>>>(ei, batch, W1, W2, gcur, gbuf, W1f, W2f, rcnts);
  k_sortgemm<<<NBKT + NGEMM, 1024, 0, stream>>>(gbuf, gcur, x, (const uint4*)W1f,
                                                deg, csr, hbuf);
  k_agg_relu<<<N_NODES / 4, 256, 0, stream>>>(hbuf, csr, deg, b1, x2);
  k_gemm2<<<NGEMM, 1024, 0, stream>>>(x2, (const uint4*)W2f, hbuf);
  k_agg_pool<<<N_NODES / 16, 1024, 0, stream>>>(hbuf, csr, deg, batch, rcnts, sums);
  k_final<<<N_GRAPHS, 128, 0, stream>>>(sums, b2, Wc, bc, out);
}